// Round 4
// baseline (286.033 us; speedup 1.0000x reference)
//
#include <hip/hip_runtime.h>
#include <hip/hip_bf16.h>
#include <math.h>

// ---------------------------------------------------------------------------
// MoNet regression on icosphere graphs.
//   * edge_dst = repeat(arange(n), 6)  -> node i owns edges [6i, 6i+6)
//   * hex_pool keeps only first L rows
//   * gmm_conv folded to node-level GEMM:
//       A[i, k*cin+c] = (1/6) sum_e w[e,k] * x[src[e], c]
//       out = relu( [A|x] @ [G'|root] + b ),  G'[k*cin+c, o] = g[c, k*cout+o]
// GEMM v3: 64x64 tile, 4x4 acc/thread (b128 LDS reads both operands),
// KG k-groups in-block split-K; KG<=2 double-buffered, KG=4 single-buffered;
// cross-group reduce aliases As/Bs. Head: deterministic split-K FC1.
// ---------------------------------------------------------------------------

#define GEPS 1e-15f

// ---------------- build_A: per-node aggregated, kernel-weighted features ----
template <int CIN>
__global__ __launch_bounds__(256) void build_A_kern(
    const float* __restrict__ x,      // (n_src, CIN)
    const int*   __restrict__ src,    // (6n)
    const float* __restrict__ pseudo, // (6n, 3)
    const float* __restrict__ mu,     // (3,3)
    const float* __restrict__ sigma,  // (3,3)
    float* __restrict__ A,            // (n, 3*CIN)
    int n)
{
    constexpr int NB = 256 / CIN;
    constexpr int NE = NB * 6;
    __shared__ float s_w[NE * 3];
    __shared__ int   s_src[NE];
    __shared__ float s_mu[9], s_sig[9];

    const int tid = threadIdx.x;
    if (tid < 9) { s_mu[tid] = mu[tid]; s_sig[tid] = sigma[tid]; }
    __syncthreads();

    const int ebase = blockIdx.x * NE;
    const int nE = n * 6;
    for (int t = tid; t < NE; t += 256) {
        int e = ebase + t;
        if (e < nE) s_src[t] = src[e];
    }
    for (int t = tid; t < NE * 3; t += 256) {
        int e_l = t / 3, k = t - e_l * 3;
        int e = ebase + e_l;
        if (e < nE) {
            float s = 0.f;
#pragma unroll
            for (int d = 0; d < 3; ++d) {
                float diff = pseudo[e * 3 + d] - s_mu[k * 3 + d];
                float sg = s_sig[k * 3 + d];
                s += diff * diff / (sg * sg + GEPS);
            }
            s_w[t] = expf(-0.5f * s);
        }
    }
    __syncthreads();

    const int il = tid / CIN;
    const int c  = tid - il * CIN;
    const int i  = blockIdx.x * NB + il;
    if (i < n) {
        float a0 = 0.f, a1 = 0.f, a2 = 0.f;
#pragma unroll
        for (int e = 0; e < 6; ++e) {
            int s = s_src[il * 6 + e];
            float xv = x[s * CIN + c];
            const float* wp = &s_w[(il * 6 + e) * 3];
            a0 += wp[0] * xv; a1 += wp[1] * xv; a2 += wp[2] * xv;
        }
        const float inv6 = 1.f / 6.f;
        float* Ai = &A[i * (3 * CIN)];
        Ai[0 * CIN + c] = a0 * inv6;
        Ai[1 * CIN + c] = a1 * inv6;
        Ai[2 * CIN + c] = a2 * inv6;
    }
}

// ---------------- GEMM v3: 64x64 tile, 4x4 acc, split-K groups --------------
#define LOAD3(kt)                                                             \
    {                                                                         \
        int jA = k0 + (kt) * 16 + lj;                                         \
        if (gi_l < n) {                                                       \
            ra = (jA < K3) ? *(const float4*)&A[gi_l * K3 + jA]               \
                           : *(const float4*)&x[gi_l * cin + (jA - K3)];      \
        } else { ra = make_float4(0.f, 0.f, 0.f, 0.f); }                      \
        int jB = k0 + (kt) * 16 + lkr;                                        \
        if (jB < K3) {                                                        \
            int kq = jB / cin, c = jB - kq * cin;                             \
            rb = *(const float4*)&g[c * (3 * cout) + kq * cout + bn + lc];    \
        } else {                                                              \
            rb = *(const float4*)&root[(jB - K3) * cout + bn + lc];           \
        }                                                                     \
    }

#define STORE3(b_)                                                            \
    {                                                                         \
        As[grp][b_][lj + 0][lr] = ra.x;                                       \
        As[grp][b_][lj + 1][lr] = ra.y;                                       \
        As[grp][b_][lj + 2][lr] = ra.z;                                       \
        As[grp][b_][lj + 3][lr] = ra.w;                                       \
        *(float4*)&Bs[grp][b_][lkr][lc] = rb;                                 \
    }

template <int KG>
__global__ __launch_bounds__(256 * KG) void gemm_node3(
    const float* __restrict__ A,    // (n, 3*cin)
    const float* __restrict__ x,    // (n, cin)
    const float* __restrict__ g,    // (cin, 3*cout)
    const float* __restrict__ root, // (cin, cout)
    const float* __restrict__ bias, // (cout)
    float* __restrict__ out,        // (n, cout)
    int n, int cin, int cout)
{
    constexpr int BUFS = (KG <= 2) ? 2 : 1;
    __shared__ float As[KG][BUFS][16][68];
    __shared__ float Bs[KG][BUFS][16][64];

    const int tid = threadIdx.x;
    const int grp = tid >> 8;
    const int t   = tid & 255;

    const int bm = blockIdx.x * 64;
    const int bn = blockIdx.y * 64;
    const int K3 = 3 * cin;
    const int KK = 4 * cin;
    const int chunk = KK / KG;
    const int k0 = grp * chunk;
    const int nkt = chunk >> 4;

    // loader lanes
    const int lr  = t & 63;          // A row
    const int lj  = (t >> 6) * 4;    // A k-offset {0,4,8,12}
    const int gi_l = bm + lr;
    const int lkr = t >> 4;          // B k-row 0..15
    const int lc  = (t & 15) * 4;    // B col float4

    // compute lanes: 4x4 per thread
    const int row0 = (t >> 4) * 4;
    const int col0 = (t & 15) * 4;

    float acc[4][4] = {};
    float4 ra, rb;

    LOAD3(0);
    STORE3(0);
    __syncthreads();

    int buf = 0;
    for (int kt = 0; kt < nkt; ++kt) {
        if (kt + 1 < nkt) LOAD3(kt + 1);   // global prefetch into regs
#pragma unroll
        for (int kk = 0; kk < 16; ++kk) {
            float4 a = *(const float4*)&As[grp][buf][kk][row0];
            float4 b = *(const float4*)&Bs[grp][buf][kk][col0];
            acc[0][0] += a.x * b.x; acc[0][1] += a.x * b.y;
            acc[0][2] += a.x * b.z; acc[0][3] += a.x * b.w;
            acc[1][0] += a.y * b.x; acc[1][1] += a.y * b.y;
            acc[1][2] += a.y * b.z; acc[1][3] += a.y * b.w;
            acc[2][0] += a.z * b.x; acc[2][1] += a.z * b.y;
            acc[2][2] += a.z * b.z; acc[2][3] += a.z * b.w;
            acc[3][0] += a.w * b.x; acc[3][1] += a.w * b.y;
            acc[3][2] += a.w * b.z; acc[3][3] += a.w * b.w;
        }
        if (kt + 1 < nkt) {
            if constexpr (BUFS == 2) {
                STORE3(buf ^ 1);
                __syncthreads();
                buf ^= 1;
            } else {
                __syncthreads();   // all groups done reading this buffer
                STORE3(0);
                __syncthreads();
            }
        }
    }

    // ---- cross-group reduction (aliases As/Bs — dead after this barrier) ---
    __syncthreads();
    float* Rs0 = (float*)As;   // 16 KB needed; As >= 17 KB for KG in {2,4}
    float* Rs1 = (float*)Bs;   // 16 KB needed; Bs >= 16 KB

#define WRITE_R(R)                                                            \
    {                                                                         \
        _Pragma("unroll")                                                     \
        for (int i2 = 0; i2 < 4; ++i2)                                        \
            *(float4*)&(R)[(row0 + i2) * 64 + col0] =                         \
                make_float4(acc[i2][0], acc[i2][1], acc[i2][2], acc[i2][3]);  \
    }
#define ADD_R(R)                                                              \
    {                                                                         \
        _Pragma("unroll")                                                     \
        for (int i2 = 0; i2 < 4; ++i2) {                                      \
            float4 r = *(const float4*)&(R)[(row0 + i2) * 64 + col0];         \
            acc[i2][0] += r.x; acc[i2][1] += r.y;                             \
            acc[i2][2] += r.z; acc[i2][3] += r.w;                             \
        }                                                                     \
    }

    if constexpr (KG >= 2) {
        if (grp == 1) WRITE_R(Rs0);
        if constexpr (KG == 4) { if (grp == 3) WRITE_R(Rs1); }
        __syncthreads();
        if (grp == 0) ADD_R(Rs0);
        if constexpr (KG == 4) {
            if (grp == 2) ADD_R(Rs1);
            __syncthreads();
            if (grp == 2) WRITE_R(Rs0);
            __syncthreads();
            if (grp == 0) ADD_R(Rs0);
        }
    }

    if (grp == 0) {
        float4 bv = *(const float4*)&bias[bn + col0];
#pragma unroll
        for (int i2 = 0; i2 < 4; ++i2) {
            int gi = bm + row0 + i2;
            if (gi < n) {
                float4 v;
                v.x = fmaxf(acc[i2][0] + bv.x, 0.f);
                v.y = fmaxf(acc[i2][1] + bv.y, 0.f);
                v.z = fmaxf(acc[i2][2] + bv.z, 0.f);
                v.w = fmaxf(acc[i2][3] + bv.w, 0.f);
                *(float4*)&out[gi * cout + bn + col0] = v;
            }
        }
    }
}

// ---------------- hex max-pool (float4 over channels) -----------------------
__global__ void hexpool_kern(const float* __restrict__ xin,
                             const int* __restrict__ hx,
                             float* __restrict__ out, int L, int C)
{
    int idx = blockIdx.x * blockDim.x + threadIdx.x;
    int C4 = C >> 2;
    int total = L * C4;
    if (idx >= total) return;
    int i = idx / C4, c4 = (idx - i * C4) * 4;
    const int* h = &hx[i * 7];
    float4 m = make_float4(-INFINITY, -INFINITY, -INFINITY, -INFINITY);
#pragma unroll
    for (int j = 0; j < 7; ++j) {
        float4 v = *(const float4*)&xin[h[j] * C + c4];
        m.x = fmaxf(m.x, v.x); m.y = fmaxf(m.y, v.y);
        m.z = fmaxf(m.z, v.z); m.w = fmaxf(m.w, v.w);
    }
    *(float4*)&out[i * C + c4] = m;
}

// ---------------- head ------------------------------------------------------
__global__ __launch_bounds__(256) void head1_kern(const float* __restrict__ xin, // (162,512)
                                                  float* __restrict__ xc)        // (1024)
{
    __shared__ float s_mx[4][64], s_sm[4][64];
    const int t = threadIdx.x;
    const int c = blockIdx.x * 64 + (t & 63);
    const int rg = t >> 6;
    float mx = -INFINITY, sm = 0.f;
    for (int r = rg; r < 162; r += 4) {
        float v = xin[r * 512 + c];
        mx = fmaxf(mx, v);
        sm += v;
    }
    s_mx[rg][t & 63] = mx; s_sm[rg][t & 63] = sm;
    __syncthreads();
    if (rg == 0) {
#pragma unroll
        for (int q = 1; q < 4; ++q) {
            mx = fmaxf(mx, s_mx[q][t]);
            sm += s_sm[q][t];
        }
        xc[c] = mx;
        xc[512 + c] = sm * (1.f / 162.f);
    }
}

__global__ __launch_bounds__(256) void fc1_part_kern(
    const float* __restrict__ xc,   // (1024)
    const float* __restrict__ fcW,  // (1024,512)
    float* __restrict__ partials)   // (8,512)
{
    __shared__ float s_p[4][64];
    const int t = threadIdx.x;
    const int o = blockIdx.x * 64 + (t & 63);
    const int jg = t >> 6;
    const int jbase = blockIdx.y * 128 + jg * 32;
    float acc = 0.f;
#pragma unroll
    for (int jj = 0; jj < 32; ++jj) {
        int j = jbase + jj;
        acc += xc[j] * fcW[j * 512 + o];
    }
    s_p[jg][t & 63] = acc;
    __syncthreads();
    if (jg == 0) {
#pragma unroll
        for (int q = 1; q < 4; ++q) acc += s_p[q][t];
        partials[blockIdx.y * 512 + o] = acc;
    }
}

__global__ __launch_bounds__(512) void head2_kern(
    const float* __restrict__ partials, // (8,512)
    const float* __restrict__ fcb,
    const float* __restrict__ fc2W,
    const float* __restrict__ fc2b,
    float* __restrict__ out)
{
    __shared__ float red[512];
    const int t = threadIdx.x;
    float p = fcb[t];
#pragma unroll
    for (int q = 0; q < 8; ++q) p += partials[q * 512 + t];
    red[t] = fmaxf(p, 0.f) * fc2W[t];
    __syncthreads();
    for (int s = 256; s > 0; s >>= 1) {
        if (t < s) red[t] += red[t + s];
        __syncthreads();
    }
    if (t == 0) out[0] = red[0] + fc2b[0];
}

// ---------------------------------------------------------------------------
extern "C" void kernel_launch(void* const* d_in, const int* in_sizes, int n_in,
                              void* d_out, int out_size, void* d_ws, size_t ws_size,
                              hipStream_t stream)
{
    const float* x0      = (const float*)d_in[0];
    const int*   src6    = (const int*)  d_in[1];
    const float* pseudo6 = (const float*)d_in[3];
    const int*   hex6    = (const int*)  d_in[4];
    const int*   src5    = (const int*)  d_in[5];
    const float* pseudo5 = (const float*)d_in[7];
    const int*   hex5    = (const int*)  d_in[8];
    const int*   src4    = (const int*)  d_in[9];
    const float* pseudo4 = (const float*)d_in[11];
    const int*   hex4    = (const int*)  d_in[12];
    const int*   src3    = (const int*)  d_in[13];
    const float* pseudo3 = (const float*)d_in[15];
    const int*   hex3    = (const int*)  d_in[16];

    const float* g1 = (const float*)d_in[17]; const float* mu1 = (const float*)d_in[18];
    const float* sg1 = (const float*)d_in[19]; const float* rt1 = (const float*)d_in[20];
    const float* b1 = (const float*)d_in[21];
    const float* g2 = (const float*)d_in[22]; const float* mu2 = (const float*)d_in[23];
    const float* sg2 = (const float*)d_in[24]; const float* rt2 = (const float*)d_in[25];
    const float* b2 = (const float*)d_in[26];
    const float* g3 = (const float*)d_in[27]; const float* mu3 = (const float*)d_in[28];
    const float* sg3 = (const float*)d_in[29]; const float* rt3 = (const float*)d_in[30];
    const float* b3 = (const float*)d_in[31];
    const float* g4 = (const float*)d_in[32]; const float* mu4 = (const float*)d_in[33];
    const float* sg4 = (const float*)d_in[34]; const float* rt4 = (const float*)d_in[35];
    const float* b4 = (const float*)d_in[36];
    const float* fcW = (const float*)d_in[37]; const float* fcb = (const float*)d_in[38];
    const float* fc2W = (const float*)d_in[39]; const float* fc2b = (const float*)d_in[40];

    float* out = (float*)d_out;

    float* ws = (float*)d_ws;
    float* A        = ws;               // up to 10242*192 = 1,966,464
    float* conv     = ws + 2000000;     // up to 40962*64  = 2,621,568
    float* pooled   = ws + 4700000;     // up to 10242*64  =   655,488
    float* xc       = ws + 5400000;     // 1024
    float* partials = ws + 5402048;     // 8*512

    // ---- level 6: n=40962, cin=4, cout=64 ----
    {
        const int n = 40962, cout = 64;
        build_A_kern<4><<<(n + 63) / 64, 256, 0, stream>>>(x0, src6, pseudo6, mu1, sg1, A, n);
        dim3 grid((n + 63) / 64, cout / 64);
        gemm_node3<1><<<grid, 256, 0, stream>>>(A, x0, g1, rt1, b1, conv, n, 4, cout);
        int L = 10242, tot = L * cout / 4;
        hexpool_kern<<<(tot + 255) / 256, 256, 0, stream>>>(conv, hex6, pooled, L, cout);
    }
    // ---- level 5: n=10242, cin=64, cout=128 ----
    {
        const int n = 10242, cout = 128;
        build_A_kern<64><<<(n + 3) / 4, 256, 0, stream>>>(pooled, src5, pseudo5, mu2, sg2, A, n);
        dim3 grid((n + 63) / 64, cout / 64);
        gemm_node3<2><<<grid, 512, 0, stream>>>(A, pooled, g2, rt2, b2, conv, n, 64, cout);
        int L = 2562, tot = L * cout / 4;
        hexpool_kern<<<(tot + 255) / 256, 256, 0, stream>>>(conv, hex5, pooled, L, cout);
    }
    // ---- level 4: n=2562, cin=128, cout=256 ----
    {
        const int n = 2562, cout = 256;
        build_A_kern<128><<<(n + 1) / 2, 256, 0, stream>>>(pooled, src4, pseudo4, mu3, sg3, A, n);
        dim3 grid((n + 63) / 64, cout / 64);
        gemm_node3<2><<<grid, 512, 0, stream>>>(A, pooled, g3, rt3, b3, conv, n, 128, cout);
        int L = 642, tot = L * cout / 4;
        hexpool_kern<<<(tot + 255) / 256, 256, 0, stream>>>(conv, hex4, pooled, L, cout);
    }
    // ---- level 3: n=642, cin=256, cout=512 ----
    {
        const int n = 642, cout = 512;
        build_A_kern<256><<<n, 256, 0, stream>>>(pooled, src3, pseudo3, mu4, sg4, A, n);
        dim3 grid((n + 63) / 64, cout / 64);
        gemm_node3<4><<<grid, 1024, 0, stream>>>(A, pooled, g4, rt4, b4, conv, n, 256, cout);
        int L = 162, tot = L * cout / 4;
        hexpool_kern<<<(tot + 255) / 256, 256, 0, stream>>>(conv, hex3, pooled, L, cout);
    }
    // ---- head ----
    head1_kern<<<8, 256, 0, stream>>>(pooled, xc);
    {
        dim3 grid(8, 8);
        fc1_part_kern<<<grid, 256, 0, stream>>>(xc, fcW, partials);
    }
    head2_kern<<<1, 512, 0, stream>>>(partials, fcb, fc2W, fc2b, out);
}

// Round 5
// 166.234 us; speedup vs baseline: 1.7207x; 1.7207x over previous
//
#include <hip/hip_runtime.h>
#include <hip/hip_bf16.h>
#include <math.h>

// ---------------------------------------------------------------------------
// MoNet regression on icosphere graphs.
//   * edge_dst = repeat(arange(n), 6)  -> node i owns edges [6i, 6i+6)
//   * hex_pool keeps only first L rows
//   * gmm_conv folded to node-level GEMM:
//       A[i, k*cin+c] = (1/6) sum_e w[e,k] * x[src[e], c]
//       out = relu( [A|x] @ [G'|root] + b ),  G'[k*cin+c, o] = g[c, k*cout+o]
// GEMM v3: 64x64 tile, 4x4 acc/thread, KG in-block split-K groups.
// KG kept <= 2 (512 threads): at 1024 threads the 64-VGPR launch-bounds cap
// spills the 4x4 accumulator to scratch (R4: 147 MB write traffic, 175 us).
// ---------------------------------------------------------------------------

#define GEPS 1e-15f

// ---------------- build_A: per-node aggregated, kernel-weighted features ----
template <int CIN>
__global__ __launch_bounds__(256) void build_A_kern(
    const float* __restrict__ x,      // (n_src, CIN)
    const int*   __restrict__ src,    // (6n)
    const float* __restrict__ pseudo, // (6n, 3)
    const float* __restrict__ mu,     // (3,3)
    const float* __restrict__ sigma,  // (3,3)
    float* __restrict__ A,            // (n, 3*CIN)
    int n)
{
    constexpr int NB = 256 / CIN;
    constexpr int NE = NB * 6;
    __shared__ float s_w[NE * 3];
    __shared__ int   s_src[NE];
    __shared__ float s_mu[9], s_sig[9];

    const int tid = threadIdx.x;
    if (tid < 9) { s_mu[tid] = mu[tid]; s_sig[tid] = sigma[tid]; }
    __syncthreads();

    const int ebase = blockIdx.x * NE;
    const int nE = n * 6;
    for (int t = tid; t < NE; t += 256) {
        int e = ebase + t;
        if (e < nE) s_src[t] = src[e];
    }
    for (int t = tid; t < NE * 3; t += 256) {
        int e_l = t / 3, k = t - e_l * 3;
        int e = ebase + e_l;
        if (e < nE) {
            float s = 0.f;
#pragma unroll
            for (int d = 0; d < 3; ++d) {
                float diff = pseudo[e * 3 + d] - s_mu[k * 3 + d];
                float sg = s_sig[k * 3 + d];
                s += diff * diff / (sg * sg + GEPS);
            }
            s_w[t] = expf(-0.5f * s);
        }
    }
    __syncthreads();

    const int il = tid / CIN;
    const int c  = tid - il * CIN;
    const int i  = blockIdx.x * NB + il;
    if (i < n) {
        float a0 = 0.f, a1 = 0.f, a2 = 0.f;
#pragma unroll
        for (int e = 0; e < 6; ++e) {
            int s = s_src[il * 6 + e];
            float xv = x[s * CIN + c];
            const float* wp = &s_w[(il * 6 + e) * 3];
            a0 += wp[0] * xv; a1 += wp[1] * xv; a2 += wp[2] * xv;
        }
        const float inv6 = 1.f / 6.f;
        float* Ai = &A[i * (3 * CIN)];
        Ai[0 * CIN + c] = a0 * inv6;
        Ai[1 * CIN + c] = a1 * inv6;
        Ai[2 * CIN + c] = a2 * inv6;
    }
}

// ---------------- GEMM v3: 64x64 tile, 4x4 acc, split-K groups (KG<=2) ------
#define LOAD3(kt)                                                             \
    {                                                                         \
        int jA = k0 + (kt) * 16 + lj;                                         \
        if (gi_l < n) {                                                       \
            ra = (jA < K3) ? *(const float4*)&A[gi_l * K3 + jA]               \
                           : *(const float4*)&x[gi_l * cin + (jA - K3)];      \
        } else { ra = make_float4(0.f, 0.f, 0.f, 0.f); }                      \
        int jB = k0 + (kt) * 16 + lkr;                                        \
        if (jB < K3) {                                                        \
            int kq = jB / cin, c = jB - kq * cin;                             \
            rb = *(const float4*)&g[c * (3 * cout) + kq * cout + bn + lc];    \
        } else {                                                              \
            rb = *(const float4*)&root[(jB - K3) * cout + bn + lc];           \
        }                                                                     \
    }

#define STORE3(b_)                                                            \
    {                                                                         \
        As[grp][b_][lj + 0][lr] = ra.x;                                       \
        As[grp][b_][lj + 1][lr] = ra.y;                                       \
        As[grp][b_][lj + 2][lr] = ra.z;                                       \
        As[grp][b_][lj + 3][lr] = ra.w;                                       \
        *(float4*)&Bs[grp][b_][lkr][lc] = rb;                                 \
    }

template <int KG>
__global__ __launch_bounds__(256 * KG) void gemm_node3(
    const float* __restrict__ A,    // (n, 3*cin)
    const float* __restrict__ x,    // (n, cin)
    const float* __restrict__ g,    // (cin, 3*cout)
    const float* __restrict__ root, // (cin, cout)
    const float* __restrict__ bias, // (cout)
    float* __restrict__ out,        // (n, cout)
    int n, int cin, int cout)
{
    __shared__ float As[KG][2][16][68];
    __shared__ float Bs[KG][2][16][64];

    const int tid = threadIdx.x;
    const int grp = tid >> 8;
    const int t   = tid & 255;

    const int bm = blockIdx.x * 64;
    const int bn = blockIdx.y * 64;
    const int K3 = 3 * cin;
    const int KK = 4 * cin;
    const int chunk = KK / KG;
    const int k0 = grp * chunk;
    const int nkt = chunk >> 4;

    // loader lanes
    const int lr  = t & 63;          // A row
    const int lj  = (t >> 6) * 4;    // A k-offset {0,4,8,12}
    const int gi_l = bm + lr;
    const int lkr = t >> 4;          // B k-row 0..15
    const int lc  = (t & 15) * 4;    // B col float4

    // compute lanes: 4x4 per thread
    const int row0 = (t >> 4) * 4;
    const int col0 = (t & 15) * 4;

    float acc[4][4] = {};
    float4 ra, rb;

    LOAD3(0);
    STORE3(0);
    __syncthreads();

    int buf = 0;
    for (int kt = 0; kt < nkt; ++kt) {
        if (kt + 1 < nkt) LOAD3(kt + 1);   // global prefetch into regs
#pragma unroll
        for (int kk = 0; kk < 16; ++kk) {
            float4 a = *(const float4*)&As[grp][buf][kk][row0];
            float4 b = *(const float4*)&Bs[grp][buf][kk][col0];
            acc[0][0] += a.x * b.x; acc[0][1] += a.x * b.y;
            acc[0][2] += a.x * b.z; acc[0][3] += a.x * b.w;
            acc[1][0] += a.y * b.x; acc[1][1] += a.y * b.y;
            acc[1][2] += a.y * b.z; acc[1][3] += a.y * b.w;
            acc[2][0] += a.z * b.x; acc[2][1] += a.z * b.y;
            acc[2][2] += a.z * b.z; acc[2][3] += a.z * b.w;
            acc[3][0] += a.w * b.x; acc[3][1] += a.w * b.y;
            acc[3][2] += a.w * b.z; acc[3][3] += a.w * b.w;
        }
        if (kt + 1 < nkt) {
            STORE3(buf ^ 1);
            __syncthreads();
            buf ^= 1;
        }
    }

    // ---- cross-group reduction (aliases As — dead after this barrier) ------
    __syncthreads();
    float* Rs0 = (float*)As;   // 16 KB needed; As is 17.4 KB per group

#define WRITE_R(R)                                                            \
    {                                                                         \
        _Pragma("unroll")                                                     \
        for (int i2 = 0; i2 < 4; ++i2)                                        \
            *(float4*)&(R)[(row0 + i2) * 64 + col0] =                         \
                make_float4(acc[i2][0], acc[i2][1], acc[i2][2], acc[i2][3]);  \
    }
#define ADD_R(R)                                                              \
    {                                                                         \
        _Pragma("unroll")                                                     \
        for (int i2 = 0; i2 < 4; ++i2) {                                      \
            float4 r = *(const float4*)&(R)[(row0 + i2) * 64 + col0];         \
            acc[i2][0] += r.x; acc[i2][1] += r.y;                             \
            acc[i2][2] += r.z; acc[i2][3] += r.w;                             \
        }                                                                     \
    }

    if constexpr (KG == 2) {
        if (grp == 1) WRITE_R(Rs0);
        __syncthreads();
        if (grp == 0) ADD_R(Rs0);
    }

    if (grp == 0) {
        float4 bv = *(const float4*)&bias[bn + col0];
#pragma unroll
        for (int i2 = 0; i2 < 4; ++i2) {
            int gi = bm + row0 + i2;
            if (gi < n) {
                float4 v;
                v.x = fmaxf(acc[i2][0] + bv.x, 0.f);
                v.y = fmaxf(acc[i2][1] + bv.y, 0.f);
                v.z = fmaxf(acc[i2][2] + bv.z, 0.f);
                v.w = fmaxf(acc[i2][3] + bv.w, 0.f);
                *(float4*)&out[gi * cout + bn + col0] = v;
            }
        }
    }
}

// ---------------- hex max-pool (float4 over channels) -----------------------
__global__ void hexpool_kern(const float* __restrict__ xin,
                             const int* __restrict__ hx,
                             float* __restrict__ out, int L, int C)
{
    int idx = blockIdx.x * blockDim.x + threadIdx.x;
    int C4 = C >> 2;
    int total = L * C4;
    if (idx >= total) return;
    int i = idx / C4, c4 = (idx - i * C4) * 4;
    const int* h = &hx[i * 7];
    float4 m = make_float4(-INFINITY, -INFINITY, -INFINITY, -INFINITY);
#pragma unroll
    for (int j = 0; j < 7; ++j) {
        float4 v = *(const float4*)&xin[h[j] * C + c4];
        m.x = fmaxf(m.x, v.x); m.y = fmaxf(m.y, v.y);
        m.z = fmaxf(m.z, v.z); m.w = fmaxf(m.w, v.w);
    }
    *(float4*)&out[i * C + c4] = m;
}

// ---------------- head ------------------------------------------------------
__global__ __launch_bounds__(256) void head1_kern(const float* __restrict__ xin, // (162,512)
                                                  float* __restrict__ xc)        // (1024)
{
    __shared__ float s_mx[4][64], s_sm[4][64];
    const int t = threadIdx.x;
    const int c = blockIdx.x * 64 + (t & 63);
    const int rg = t >> 6;
    float mx = -INFINITY, sm = 0.f;
    for (int r = rg; r < 162; r += 4) {
        float v = xin[r * 512 + c];
        mx = fmaxf(mx, v);
        sm += v;
    }
    s_mx[rg][t & 63] = mx; s_sm[rg][t & 63] = sm;
    __syncthreads();
    if (rg == 0) {
#pragma unroll
        for (int q = 1; q < 4; ++q) {
            mx = fmaxf(mx, s_mx[q][t]);
            sm += s_sm[q][t];
        }
        xc[c] = mx;
        xc[512 + c] = sm * (1.f / 162.f);
    }
}

__global__ __launch_bounds__(256) void fc1_part_kern(
    const float* __restrict__ xc,   // (1024)
    const float* __restrict__ fcW,  // (1024,512)
    float* __restrict__ partials)   // (8,512)
{
    __shared__ float s_p[4][64];
    const int t = threadIdx.x;
    const int o = blockIdx.x * 64 + (t & 63);
    const int jg = t >> 6;
    const int jbase = blockIdx.y * 128 + jg * 32;
    float acc = 0.f;
#pragma unroll
    for (int jj = 0; jj < 32; ++jj) {
        int j = jbase + jj;
        acc += xc[j] * fcW[j * 512 + o];
    }
    s_p[jg][t & 63] = acc;
    __syncthreads();
    if (jg == 0) {
#pragma unroll
        for (int q = 1; q < 4; ++q) acc += s_p[q][t];
        partials[blockIdx.y * 512 + o] = acc;
    }
}

__global__ __launch_bounds__(512) void head2_kern(
    const float* __restrict__ partials, // (8,512)
    const float* __restrict__ fcb,
    const float* __restrict__ fc2W,
    const float* __restrict__ fc2b,
    float* __restrict__ out)
{
    __shared__ float red[512];
    const int t = threadIdx.x;
    float p = fcb[t];
#pragma unroll
    for (int q = 0; q < 8; ++q) p += partials[q * 512 + t];
    red[t] = fmaxf(p, 0.f) * fc2W[t];
    __syncthreads();
    for (int s = 256; s > 0; s >>= 1) {
        if (t < s) red[t] += red[t + s];
        __syncthreads();
    }
    if (t == 0) out[0] = red[0] + fc2b[0];
}

// ---------------------------------------------------------------------------
extern "C" void kernel_launch(void* const* d_in, const int* in_sizes, int n_in,
                              void* d_out, int out_size, void* d_ws, size_t ws_size,
                              hipStream_t stream)
{
    const float* x0      = (const float*)d_in[0];
    const int*   src6    = (const int*)  d_in[1];
    const float* pseudo6 = (const float*)d_in[3];
    const int*   hex6    = (const int*)  d_in[4];
    const int*   src5    = (const int*)  d_in[5];
    const float* pseudo5 = (const float*)d_in[7];
    const int*   hex5    = (const int*)  d_in[8];
    const int*   src4    = (const int*)  d_in[9];
    const float* pseudo4 = (const float*)d_in[11];
    const int*   hex4    = (const int*)  d_in[12];
    const int*   src3    = (const int*)  d_in[13];
    const float* pseudo3 = (const float*)d_in[15];
    const int*   hex3    = (const int*)  d_in[16];

    const float* g1 = (const float*)d_in[17]; const float* mu1 = (const float*)d_in[18];
    const float* sg1 = (const float*)d_in[19]; const float* rt1 = (const float*)d_in[20];
    const float* b1 = (const float*)d_in[21];
    const float* g2 = (const float*)d_in[22]; const float* mu2 = (const float*)d_in[23];
    const float* sg2 = (const float*)d_in[24]; const float* rt2 = (const float*)d_in[25];
    const float* b2 = (const float*)d_in[26];
    const float* g3 = (const float*)d_in[27]; const float* mu3 = (const float*)d_in[28];
    const float* sg3 = (const float*)d_in[29]; const float* rt3 = (const float*)d_in[30];
    const float* b3 = (const float*)d_in[31];
    const float* g4 = (const float*)d_in[32]; const float* mu4 = (const float*)d_in[33];
    const float* sg4 = (const float*)d_in[34]; const float* rt4 = (const float*)d_in[35];
    const float* b4 = (const float*)d_in[36];
    const float* fcW = (const float*)d_in[37]; const float* fcb = (const float*)d_in[38];
    const float* fc2W = (const float*)d_in[39]; const float* fc2b = (const float*)d_in[40];

    float* out = (float*)d_out;

    float* ws = (float*)d_ws;
    float* A        = ws;               // up to 10242*192 = 1,966,464
    float* conv     = ws + 2000000;     // up to 40962*64  = 2,621,568
    float* pooled   = ws + 4700000;     // up to 10242*64  =   655,488
    float* xc       = ws + 5400000;     // 1024
    float* partials = ws + 5402048;     // 8*512

    // ---- level 6: n=40962, cin=4, cout=64 ----
    {
        const int n = 40962, cout = 64;
        build_A_kern<4><<<(n + 63) / 64, 256, 0, stream>>>(x0, src6, pseudo6, mu1, sg1, A, n);
        dim3 grid((n + 63) / 64, cout / 64);
        gemm_node3<1><<<grid, 256, 0, stream>>>(A, x0, g1, rt1, b1, conv, n, 4, cout);
        int L = 10242, tot = L * cout / 4;
        hexpool_kern<<<(tot + 255) / 256, 256, 0, stream>>>(conv, hex6, pooled, L, cout);
    }
    // ---- level 5: n=10242, cin=64, cout=128 ----
    {
        const int n = 10242, cout = 128;
        build_A_kern<64><<<(n + 3) / 4, 256, 0, stream>>>(pooled, src5, pseudo5, mu2, sg2, A, n);
        dim3 grid((n + 63) / 64, cout / 64);
        gemm_node3<2><<<grid, 512, 0, stream>>>(A, pooled, g2, rt2, b2, conv, n, 64, cout);
        int L = 2562, tot = L * cout / 4;
        hexpool_kern<<<(tot + 255) / 256, 256, 0, stream>>>(conv, hex5, pooled, L, cout);
    }
    // ---- level 4: n=2562, cin=128, cout=256 ----
    {
        const int n = 2562, cout = 256;
        build_A_kern<128><<<(n + 1) / 2, 256, 0, stream>>>(pooled, src4, pseudo4, mu3, sg3, A, n);
        dim3 grid((n + 63) / 64, cout / 64);
        gemm_node3<2><<<grid, 512, 0, stream>>>(A, pooled, g3, rt3, b3, conv, n, 128, cout);
        int L = 642, tot = L * cout / 4;
        hexpool_kern<<<(tot + 255) / 256, 256, 0, stream>>>(conv, hex4, pooled, L, cout);
    }
    // ---- level 3: n=642, cin=256, cout=512 ----  (KG=2: 512 threads, no spill)
    {
        const int n = 642, cout = 512;
        build_A_kern<256><<<n, 256, 0, stream>>>(pooled, src3, pseudo3, mu4, sg4, A, n);
        dim3 grid((n + 63) / 64, cout / 64);
        gemm_node3<2><<<grid, 512, 0, stream>>>(A, pooled, g4, rt4, b4, conv, n, 256, cout);
        int L = 162, tot = L * cout / 4;
        hexpool_kern<<<(tot + 255) / 256, 256, 0, stream>>>(conv, hex3, pooled, L, cout);
    }
    // ---- head ----
    head1_kern<<<8, 256, 0, stream>>>(pooled, xc);
    {
        dim3 grid(8, 8);
        fc1_part_kern<<<grid, 256, 0, stream>>>(xc, fcW, partials);
    }
    head2_kern<<<1, 512, 0, stream>>>(partials, fcb, fc2W, fc2b, out);
}

// Round 6
// 149.692 us; speedup vs baseline: 1.9108x; 1.1105x over previous
//
#include <hip/hip_runtime.h>
#include <hip/hip_bf16.h>
#include <math.h>

// ---------------------------------------------------------------------------
// MoNet regression on icosphere graphs.
//   * edge_dst = repeat(arange(n), 6)  -> node i owns edges [6i, 6i+6)
//   * hex_pool keeps only first L rows
//   * gmm_conv folded to node-level GEMM:
//       A[i, k*cin+c] = (1/6) sum_e w[e,k] * x[src[e], c]
//       out = relu( [A|x] @ [G'|root] + b ),  G'[k*cin+c, o] = g[c, k*cout+o]
// GEMM v4: 64x64 tile, 4x4 acc/thread, KG<=2 in-block k-groups (512 threads;
// 1024 threads spills acc under the 64-VGPR cap — R4 lesson), plus
// grid.z split-K writing raw partials + a float4 reduce(+bias+relu) kernel
// for the small-M levels (L3/L4) that otherwise leave 2/3 of the chip idle.
// ---------------------------------------------------------------------------

#define GEPS 1e-15f

// ---------------- build_A: per-node aggregated, kernel-weighted features ----
template <int CIN>
__global__ __launch_bounds__(256) void build_A_kern(
    const float* __restrict__ x,      // (n_src, CIN)
    const int*   __restrict__ src,    // (6n)
    const float* __restrict__ pseudo, // (6n, 3)
    const float* __restrict__ mu,     // (3,3)
    const float* __restrict__ sigma,  // (3,3)
    float* __restrict__ A,            // (n, 3*CIN)
    int n)
{
    constexpr int NB = 256 / CIN;
    constexpr int NE = NB * 6;
    __shared__ float s_w[NE * 3];
    __shared__ int   s_src[NE];
    __shared__ float s_mu[9], s_sig[9];

    const int tid = threadIdx.x;
    if (tid < 9) { s_mu[tid] = mu[tid]; s_sig[tid] = sigma[tid]; }
    __syncthreads();

    const int ebase = blockIdx.x * NE;
    const int nE = n * 6;
    for (int t = tid; t < NE; t += 256) {
        int e = ebase + t;
        if (e < nE) s_src[t] = src[e];
    }
    for (int t = tid; t < NE * 3; t += 256) {
        int e_l = t / 3, k = t - e_l * 3;
        int e = ebase + e_l;
        if (e < nE) {
            float s = 0.f;
#pragma unroll
            for (int d = 0; d < 3; ++d) {
                float diff = pseudo[e * 3 + d] - s_mu[k * 3 + d];
                float sg = s_sig[k * 3 + d];
                s += diff * diff / (sg * sg + GEPS);
            }
            s_w[t] = expf(-0.5f * s);
        }
    }
    __syncthreads();

    const int il = tid / CIN;
    const int c  = tid - il * CIN;
    const int i  = blockIdx.x * NB + il;
    if (i < n) {
        float a0 = 0.f, a1 = 0.f, a2 = 0.f;
#pragma unroll
        for (int e = 0; e < 6; ++e) {
            int s = s_src[il * 6 + e];
            float xv = x[s * CIN + c];
            const float* wp = &s_w[(il * 6 + e) * 3];
            a0 += wp[0] * xv; a1 += wp[1] * xv; a2 += wp[2] * xv;
        }
        const float inv6 = 1.f / 6.f;
        float* Ai = &A[i * (3 * CIN)];
        Ai[0 * CIN + c] = a0 * inv6;
        Ai[1 * CIN + c] = a1 * inv6;
        Ai[2 * CIN + c] = a2 * inv6;
    }
}

// ---------------- GEMM v4: 64x64 tile, 4x4 acc, KG in-block + grid.z split-K
#define LOAD3(kt)                                                             \
    {                                                                         \
        int jA = k0 + (kt) * 16 + lj;                                         \
        if (gi_l < n) {                                                       \
            ra = (jA < K3) ? *(const float4*)&A[gi_l * K3 + jA]               \
                           : *(const float4*)&x[gi_l * cin + (jA - K3)];      \
        } else { ra = make_float4(0.f, 0.f, 0.f, 0.f); }                      \
        int jB = k0 + (kt) * 16 + lkr;                                        \
        if (jB < K3) {                                                        \
            int kq = jB / cin, c = jB - kq * cin;                             \
            rb = *(const float4*)&g[c * (3 * cout) + kq * cout + bn + lc];    \
        } else {                                                              \
            rb = *(const float4*)&root[(jB - K3) * cout + bn + lc];           \
        }                                                                     \
    }

#define STORE3(b_)                                                            \
    {                                                                         \
        As[grp][b_][lj + 0][lr] = ra.x;                                       \
        As[grp][b_][lj + 1][lr] = ra.y;                                       \
        As[grp][b_][lj + 2][lr] = ra.z;                                       \
        As[grp][b_][lj + 3][lr] = ra.w;                                       \
        *(float4*)&Bs[grp][b_][lkr][lc] = rb;                                 \
    }

template <int KG, bool SPLIT>
__global__ __launch_bounds__(256 * KG) void gemm_node4(
    const float* __restrict__ A,    // (n, 3*cin)
    const float* __restrict__ x,    // (n, cin)
    const float* __restrict__ g,    // (cin, 3*cout)
    const float* __restrict__ root, // (cin, cout)
    const float* __restrict__ bias, // (cout)   (unused when SPLIT)
    float* __restrict__ out,        // (n, cout) or partials (nz, n, cout)
    int n, int cin, int cout)
{
    __shared__ float As[KG][2][16][68];
    __shared__ float Bs[KG][2][16][64];

    const int tid = threadIdx.x;
    const int grp = tid >> 8;
    const int t   = tid & 255;

    const int bm = blockIdx.x * 64;
    const int bn = blockIdx.y * 64;
    const int K3 = 3 * cin;
    const int KK = 4 * cin;
    const int nz = SPLIT ? gridDim.z : 1;
    const int chunk = KK / (nz * KG);
    const int k0 = (blockIdx.z * KG + grp) * chunk;
    const int nkt = chunk >> 4;

    // loader lanes
    const int lr  = t & 63;          // A row
    const int lj  = (t >> 6) * 4;    // A k-offset {0,4,8,12}
    const int gi_l = bm + lr;
    const int lkr = t >> 4;          // B k-row 0..15
    const int lc  = (t & 15) * 4;    // B col float4

    // compute lanes: 4x4 per thread
    const int row0 = (t >> 4) * 4;
    const int col0 = (t & 15) * 4;

    float acc[4][4] = {};
    float4 ra, rb;

    LOAD3(0);
    STORE3(0);
    __syncthreads();

    int buf = 0;
    for (int kt = 0; kt < nkt; ++kt) {
        if (kt + 1 < nkt) LOAD3(kt + 1);   // global prefetch into regs
#pragma unroll
        for (int kk = 0; kk < 16; ++kk) {
            float4 a = *(const float4*)&As[grp][buf][kk][row0];
            float4 b = *(const float4*)&Bs[grp][buf][kk][col0];
            acc[0][0] += a.x * b.x; acc[0][1] += a.x * b.y;
            acc[0][2] += a.x * b.z; acc[0][3] += a.x * b.w;
            acc[1][0] += a.y * b.x; acc[1][1] += a.y * b.y;
            acc[1][2] += a.y * b.z; acc[1][3] += a.y * b.w;
            acc[2][0] += a.z * b.x; acc[2][1] += a.z * b.y;
            acc[2][2] += a.z * b.z; acc[2][3] += a.z * b.w;
            acc[3][0] += a.w * b.x; acc[3][1] += a.w * b.y;
            acc[3][2] += a.w * b.z; acc[3][3] += a.w * b.w;
        }
        if (kt + 1 < nkt) {
            STORE3(buf ^ 1);
            __syncthreads();
            buf ^= 1;
        }
    }

    // ---- cross-group reduction (aliases As — dead after this barrier) ------
    __syncthreads();
    float* Rs0 = (float*)As;

#define WRITE_R(R)                                                            \
    {                                                                         \
        _Pragma("unroll")                                                     \
        for (int i2 = 0; i2 < 4; ++i2)                                        \
            *(float4*)&(R)[(row0 + i2) * 64 + col0] =                         \
                make_float4(acc[i2][0], acc[i2][1], acc[i2][2], acc[i2][3]);  \
    }
#define ADD_R(R)                                                              \
    {                                                                         \
        _Pragma("unroll")                                                     \
        for (int i2 = 0; i2 < 4; ++i2) {                                      \
            float4 r = *(const float4*)&(R)[(row0 + i2) * 64 + col0];         \
            acc[i2][0] += r.x; acc[i2][1] += r.y;                             \
            acc[i2][2] += r.z; acc[i2][3] += r.w;                             \
        }                                                                     \
    }

    if constexpr (KG == 2) {
        if (grp == 1) WRITE_R(Rs0);
        __syncthreads();
        if (grp == 0) ADD_R(Rs0);
    }

    if (grp == 0) {
        if constexpr (SPLIT) {
            float* po = &out[(size_t)blockIdx.z * n * cout];
#pragma unroll
            for (int i2 = 0; i2 < 4; ++i2) {
                int gi = bm + row0 + i2;
                if (gi < n)
                    *(float4*)&po[gi * cout + bn + col0] =
                        make_float4(acc[i2][0], acc[i2][1], acc[i2][2], acc[i2][3]);
            }
        } else {
            float4 bv = *(const float4*)&bias[bn + col0];
#pragma unroll
            for (int i2 = 0; i2 < 4; ++i2) {
                int gi = bm + row0 + i2;
                if (gi < n) {
                    float4 v;
                    v.x = fmaxf(acc[i2][0] + bv.x, 0.f);
                    v.y = fmaxf(acc[i2][1] + bv.y, 0.f);
                    v.z = fmaxf(acc[i2][2] + bv.z, 0.f);
                    v.w = fmaxf(acc[i2][3] + bv.w, 0.f);
                    *(float4*)&out[gi * cout + bn + col0] = v;
                }
            }
        }
    }
}

// ---------------- reduce z-partials + bias + relu ---------------------------
__global__ __launch_bounds__(256) void reduce_kern(
    const float* __restrict__ part,  // (nz, n, cout)
    const float* __restrict__ bias,  // (cout)
    float* __restrict__ out,         // (n, cout)
    int n, int cout, int nz)
{
    int idx = blockIdx.x * blockDim.x + threadIdx.x;     // float4 index
    int c4 = cout >> 2;
    int total = n * c4;
    if (idx >= total) return;
    int col4 = (idx % c4) * 4;
    float4 s = *(const float4*)&bias[col4];
    size_t stride = (size_t)n * cout;
    for (int z = 0; z < nz; ++z) {
        float4 p = *(const float4*)&part[z * stride + (size_t)idx * 4];
        s.x += p.x; s.y += p.y; s.z += p.z; s.w += p.w;
    }
    s.x = fmaxf(s.x, 0.f); s.y = fmaxf(s.y, 0.f);
    s.z = fmaxf(s.z, 0.f); s.w = fmaxf(s.w, 0.f);
    *(float4*)&out[(size_t)idx * 4] = s;
}

// ---------------- hex max-pool (float4 over channels) -----------------------
__global__ void hexpool_kern(const float* __restrict__ xin,
                             const int* __restrict__ hx,
                             float* __restrict__ out, int L, int C)
{
    int idx = blockIdx.x * blockDim.x + threadIdx.x;
    int C4 = C >> 2;
    int total = L * C4;
    if (idx >= total) return;
    int i = idx / C4, c4 = (idx - i * C4) * 4;
    const int* h = &hx[i * 7];
    float4 m = make_float4(-INFINITY, -INFINITY, -INFINITY, -INFINITY);
#pragma unroll
    for (int j = 0; j < 7; ++j) {
        float4 v = *(const float4*)&xin[h[j] * C + c4];
        m.x = fmaxf(m.x, v.x); m.y = fmaxf(m.y, v.y);
        m.z = fmaxf(m.z, v.z); m.w = fmaxf(m.w, v.w);
    }
    *(float4*)&out[i * C + c4] = m;
}

// ---------------- head ------------------------------------------------------
__global__ __launch_bounds__(256) void head1_kern(const float* __restrict__ xin, // (162,512)
                                                  float* __restrict__ xc)        // (1024)
{
    __shared__ float s_mx[4][64], s_sm[4][64];
    const int t = threadIdx.x;
    const int c = blockIdx.x * 64 + (t & 63);
    const int rg = t >> 6;
    float mx = -INFINITY, sm = 0.f;
    for (int r = rg; r < 162; r += 4) {
        float v = xin[r * 512 + c];
        mx = fmaxf(mx, v);
        sm += v;
    }
    s_mx[rg][t & 63] = mx; s_sm[rg][t & 63] = sm;
    __syncthreads();
    if (rg == 0) {
#pragma unroll
        for (int q = 1; q < 4; ++q) {
            mx = fmaxf(mx, s_mx[q][t]);
            sm += s_sm[q][t];
        }
        xc[c] = mx;
        xc[512 + c] = sm * (1.f / 162.f);
    }
}

__global__ __launch_bounds__(256) void fc1_part_kern(
    const float* __restrict__ xc,   // (1024)
    const float* __restrict__ fcW,  // (1024,512)
    float* __restrict__ partials)   // (8,512)
{
    __shared__ float s_p[4][64];
    const int t = threadIdx.x;
    const int o = blockIdx.x * 64 + (t & 63);
    const int jg = t >> 6;
    const int jbase = blockIdx.y * 128 + jg * 32;
    float acc = 0.f;
#pragma unroll
    for (int jj = 0; jj < 32; ++jj) {
        int j = jbase + jj;
        acc += xc[j] * fcW[j * 512 + o];
    }
    s_p[jg][t & 63] = acc;
    __syncthreads();
    if (jg == 0) {
#pragma unroll
        for (int q = 1; q < 4; ++q) acc += s_p[q][t];
        partials[blockIdx.y * 512 + o] = acc;
    }
}

__global__ __launch_bounds__(512) void head2_kern(
    const float* __restrict__ partials, // (8,512)
    const float* __restrict__ fcb,
    const float* __restrict__ fc2W,
    const float* __restrict__ fc2b,
    float* __restrict__ out)
{
    __shared__ float red[512];
    const int t = threadIdx.x;
    float p = fcb[t];
#pragma unroll
    for (int q = 0; q < 8; ++q) p += partials[q * 512 + t];
    red[t] = fmaxf(p, 0.f) * fc2W[t];
    __syncthreads();
    for (int s = 256; s > 0; s >>= 1) {
        if (t < s) red[t] += red[t + s];
        __syncthreads();
    }
    if (t == 0) out[0] = red[0] + fc2b[0];
}

// ---------------------------------------------------------------------------
extern "C" void kernel_launch(void* const* d_in, const int* in_sizes, int n_in,
                              void* d_out, int out_size, void* d_ws, size_t ws_size,
                              hipStream_t stream)
{
    const float* x0      = (const float*)d_in[0];
    const int*   src6    = (const int*)  d_in[1];
    const float* pseudo6 = (const float*)d_in[3];
    const int*   hex6    = (const int*)  d_in[4];
    const int*   src5    = (const int*)  d_in[5];
    const float* pseudo5 = (const float*)d_in[7];
    const int*   hex5    = (const int*)  d_in[8];
    const int*   src4    = (const int*)  d_in[9];
    const float* pseudo4 = (const float*)d_in[11];
    const int*   hex4    = (const int*)  d_in[12];
    const int*   src3    = (const int*)  d_in[13];
    const float* pseudo3 = (const float*)d_in[15];
    const int*   hex3    = (const int*)  d_in[16];

    const float* g1 = (const float*)d_in[17]; const float* mu1 = (const float*)d_in[18];
    const float* sg1 = (const float*)d_in[19]; const float* rt1 = (const float*)d_in[20];
    const float* b1 = (const float*)d_in[21];
    const float* g2 = (const float*)d_in[22]; const float* mu2 = (const float*)d_in[23];
    const float* sg2 = (const float*)d_in[24]; const float* rt2 = (const float*)d_in[25];
    const float* b2 = (const float*)d_in[26];
    const float* g3 = (const float*)d_in[27]; const float* mu3 = (const float*)d_in[28];
    const float* sg3 = (const float*)d_in[29]; const float* rt3 = (const float*)d_in[30];
    const float* b3 = (const float*)d_in[31];
    const float* g4 = (const float*)d_in[32]; const float* mu4 = (const float*)d_in[33];
    const float* sg4 = (const float*)d_in[34]; const float* rt4 = (const float*)d_in[35];
    const float* b4 = (const float*)d_in[36];
    const float* fcW = (const float*)d_in[37]; const float* fcb = (const float*)d_in[38];
    const float* fc2W = (const float*)d_in[39]; const float* fc2b = (const float*)d_in[40];

    float* out = (float*)d_out;

    float* ws = (float*)d_ws;
    float* A        = ws;               // up to 10242*192 = 1,966,464
    float* conv     = ws + 2000000;     // up to 40962*64  = 2,621,568
    float* pooled   = ws + 4700000;     // up to 10242*64  =   655,488
    float* xc       = ws + 5400000;     // 1024
    float* fcpart   = ws + 5402048;     // 8*512
    float* gpart    = ws + 5500000;     // up to 4*642*512 = 1,314,816

    // ---- level 6: n=40962, cin=4, cout=64 ----
    {
        const int n = 40962, cout = 64;
        build_A_kern<4><<<(n + 63) / 64, 256, 0, stream>>>(x0, src6, pseudo6, mu1, sg1, A, n);
        dim3 grid((n + 63) / 64, cout / 64);
        gemm_node4<1, false><<<grid, 256, 0, stream>>>(A, x0, g1, rt1, b1, conv, n, 4, cout);
        int L = 10242, tot = L * cout / 4;
        hexpool_kern<<<(tot + 255) / 256, 256, 0, stream>>>(conv, hex6, pooled, L, cout);
    }
    // ---- level 5: n=10242, cin=64, cout=128 ----
    {
        const int n = 10242, cout = 128;
        build_A_kern<64><<<(n + 3) / 4, 256, 0, stream>>>(pooled, src5, pseudo5, mu2, sg2, A, n);
        dim3 grid((n + 63) / 64, cout / 64);
        gemm_node4<2, false><<<grid, 512, 0, stream>>>(A, pooled, g2, rt2, b2, conv, n, 64, cout);
        int L = 2562, tot = L * cout / 4;
        hexpool_kern<<<(tot + 255) / 256, 256, 0, stream>>>(conv, hex5, pooled, L, cout);
    }
    // ---- level 4: n=2562, cin=128, cout=256 ----  grid.z=2 split-K
    {
        const int n = 2562, cout = 256;
        build_A_kern<128><<<(n + 1) / 2, 256, 0, stream>>>(pooled, src4, pseudo4, mu3, sg3, A, n);
        dim3 grid((n + 63) / 64, cout / 64, 2);
        gemm_node4<2, true><<<grid, 512, 0, stream>>>(A, pooled, g3, rt3, b3, gpart, n, 128, cout);
        int tot4 = n * cout / 4;
        reduce_kern<<<(tot4 + 255) / 256, 256, 0, stream>>>(gpart, b3, conv, n, cout, 2);
        int L = 642, tot = L * cout / 4;
        hexpool_kern<<<(tot + 255) / 256, 256, 0, stream>>>(conv, hex4, pooled, L, cout);
    }
    // ---- level 3: n=642, cin=256, cout=512 ----  grid.z=4 split-K
    {
        const int n = 642, cout = 512;
        build_A_kern<256><<<n, 256, 0, stream>>>(pooled, src3, pseudo3, mu4, sg4, A, n);
        dim3 grid((n + 63) / 64, cout / 64, 4);
        gemm_node4<2, true><<<grid, 512, 0, stream>>>(A, pooled, g4, rt4, b4, gpart, n, 256, cout);
        int tot4 = n * cout / 4;
        reduce_kern<<<(tot4 + 255) / 256, 256, 0, stream>>>(gpart, b4, conv, n, cout, 4);
        int L = 162, tot = L * cout / 4;
        hexpool_kern<<<(tot + 255) / 256, 256, 0, stream>>>(conv, hex3, pooled, L, cout);
    }
    // ---- head ----
    head1_kern<<<8, 256, 0, stream>>>(pooled, xc);
    {
        dim3 grid(8, 8);
        fc1_part_kern<<<grid, 256, 0, stream>>>(xc, fcW, fcpart);
    }
    head2_kern<<<1, 512, 0, stream>>>(fcpart, fcb, fc2W, fc2b, out);
}